// Round 6
// baseline (369.644 us; speedup 1.0000x reference)
//
#include <hip/hip_runtime.h>
#include <hip/hip_bf16.h>

#define NN 16000
#define EE 256000
#define CC 64
#define AA 10
#define RR 8
#define NC9 9216000      // N*C*9
#define SC_OFF 18432000  // 2*N*C*9

// ---------------- workspace layout (bytes) ----------------
#define WS_H        0
#define WS_BLK      4096000
#define WS_WLT      32768000
#define WS_SPECIES  32817152
#define WS_COUNTS   32881152
#define WS_CURSOR   32945152
#define WS_OFFSETS  33009152
#define WS_ELIST    33073216
// end ~34.1 MB

__global__ __launch_bounds__(256) void species_kernel(
    const float* __restrict__ attrs, int* __restrict__ species) {
  int i = blockIdx.x * 256 + threadIdx.x;
  if (i >= NN) return;
  const float* p = attrs + (size_t)i * AA;
  int sp = 0;
#pragma unroll
  for (int a = 1; a < AA; ++a)
    if (p[a] > 0.5f) sp = a;
  species[i] = sp;
}

// h = (nf @ W_up)/8 ; sc = (nf . W_skip[:,a,:])/sqrt(640)
__global__ __launch_bounds__(256) void node_kernel(
    const float* __restrict__ nf, const int* __restrict__ species,
    const float* __restrict__ W_up, const float* __restrict__ W_skip,
    float* __restrict__ h, float* __restrict__ out) {
  int wid = __builtin_amdgcn_readfirstlane(threadIdx.x >> 6);
  int lane = threadIdx.x & 63;
  int n = blockIdx.x * 4 + wid;
  int a = species[n];
  const float* nfp = nf + (size_t)n * 64;
  const float* wsk = W_skip + (size_t)a * 64;  // + u*640 + lane
  float hacc = 0.f, sacc = 0.f;
#pragma unroll
  for (int u = 0; u < 64; ++u) {
    float x = nfp[u];  // wave-uniform -> scalar load
    hacc = fmaf(x, W_up[u * 64 + lane], hacc);
    sacc = fmaf(x, wsk[u * 640 + lane], sacc);
  }
  h[(size_t)n * 64 + lane] = hacc * 0.125f;
  out[SC_OFF + (size_t)n * 64 + lane] = sacc * 0.03952847075210474f;
}

// W_linT[l][v][u] = W_lin[l][u][v]
__global__ __launch_bounds__(256) void wlint_kernel(
    const float* __restrict__ W_lin, float* __restrict__ W_linT) {
  int idx = blockIdx.x * 256 + threadIdx.x;
  if (idx >= 3 * 64 * 64) return;
  int l = idx >> 12, rem = idx & 4095, v = rem >> 6, u = rem & 63;
  W_linT[idx] = W_lin[l * 4096 + u * 64 + v];
}

__global__ __launch_bounds__(256) void hist_kernel(
    const int* __restrict__ recv, int* __restrict__ counts) {
  int e = blockIdx.x * 256 + threadIdx.x;
  if (e < EE) atomicAdd(&counts[recv[e]], 1);
}

// single-block exclusive scan of counts[N] -> offsets[N+1]
__global__ __launch_bounds__(1024) void scan_kernel(
    const int* __restrict__ counts, int* __restrict__ offsets) {
  __shared__ int part[1024];
  int tid = threadIdx.x;
  const int CH = 16;  // 1024*16 = 16384 >= 16001
  int base = tid * CH;
  int loc[CH];
  int s = 0;
#pragma unroll
  for (int i = 0; i < CH; ++i) {
    int idx = base + i;
    int c = (idx < NN) ? counts[idx] : 0;
    loc[i] = c;
    s += c;
  }
  part[tid] = s;
  __syncthreads();
  for (int off = 1; off < 1024; off <<= 1) {
    int t = part[tid];
    int add = (tid >= off) ? part[tid - off] : 0;
    __syncthreads();
    part[tid] = t + add;
    __syncthreads();
  }
  int pre = (tid > 0) ? part[tid - 1] : 0;
#pragma unroll
  for (int i = 0; i < CH; ++i) {
    int idx = base + i;
    if (idx <= NN) offsets[idx] = pre;
    pre += loc[i];
  }
}

// CSR slot fill: only edge ids (4B scattered writes)
__global__ __launch_bounds__(256) void fill_slots_kernel(
    const int* __restrict__ recv, const int* __restrict__ offsets,
    int* __restrict__ cursor, int* __restrict__ elist) {
  int e = blockIdx.x * 256 + threadIdx.x;
  if (e >= EE) return;
  int r = recv[e];
  int pos = atomicAdd(&cursor[r], 1);
  elist[offsets[r] + pos] = e;
}

// build packed 112-B per-EDGE block (coalesced writes, edge order):
// dw0 = s|(a<<20); dw1-8 = ef; dw9-17 = er; dw18-26 = ei; dw27 pad
__global__ __launch_bounds__(256) void build_blk_kernel(
    const int* __restrict__ senders, const int* __restrict__ species,
    const float* __restrict__ ef, const float* __restrict__ ear,
    const float* __restrict__ eai, float* __restrict__ blk) {
  int e = blockIdx.x * 256 + threadIdx.x;
  if (e >= EE) return;
  int s = senders[e];
  int a = species[s];
  const float* efp = ef + (size_t)e * 8;
  const float* erp = ear + (size_t)e * 9;
  const float* eip = eai + (size_t)e * 9;
  float4* dst = (float4*)(blk + (size_t)e * 28);
  float4 q;
  q.x = __int_as_float(s | (a << 20)); q.y = efp[0]; q.z = efp[1]; q.w = efp[2];
  dst[0] = q;
  q.x = efp[3]; q.y = efp[4]; q.z = efp[5]; q.w = efp[6];
  dst[1] = q;
  q.x = efp[7]; q.y = erp[0]; q.z = erp[1]; q.w = erp[2];
  dst[2] = q;
  q.x = erp[3]; q.y = erp[4]; q.z = erp[5]; q.w = erp[6];
  dst[3] = q;
  q.x = erp[7]; q.y = erp[8]; q.z = eip[0]; q.w = eip[1];
  dst[4] = q;
  q.x = eip[2]; q.y = eip[3]; q.z = eip[4]; q.w = eip[5];
  dst[5] = q;
  q.x = eip[6]; q.y = eip[7]; q.z = eip[8]; q.w = 0.f;
  dst[6] = q;
}

#define RL(V, L) __builtin_amdgcn_readlane((V), (L))
#define RLF(V, L) __int_as_float(__builtin_amdgcn_readlane((V), (L)))

// one EDGE: BLK = pair dwords (lane-distributed), OFF = 0 or 28, XS = h[s][lane]
#define EDGE(BLK, OFF, XS) do {                                            \
  float efs[8], ers[9], eis[9];                                            \
  _Pragma("unroll") for (int i_ = 0; i_ < 8; ++i_)                         \
    efs[i_] = RLF((BLK), (OFF) + 1 + i_);                                  \
  _Pragma("unroll") for (int i_ = 0; i_ < 9; ++i_)                         \
    ers[i_] = RLF((BLK), (OFF) + 9 + i_);                                  \
  _Pragma("unroll") for (int i_ = 0; i_ < 9; ++i_)                         \
    eis[i_] = RLF((BLK), (OFF) + 18 + i_);                                 \
  int a_ = RL((BLK), (OFF)) >> 20;                                         \
  const float4* wp_ = (const float4*)(lds + a_ * 1792 + lane * 28);        \
  float4 w0_ = wp_[gpi[0]], w1_ = wp_[gpi[1]], w2_ = wp_[gpi[2]];          \
  float4 w3_ = wp_[gpi[3]], w4_ = wp_[gpi[4]], w5_ = wp_[gpi[5]];          \
  const float wv_[24] = {w0_.x, w0_.y, w0_.z, w0_.w, w1_.x, w1_.y, w1_.z,  \
                         w1_.w, w2_.x, w2_.y, w2_.z, w2_.w, w3_.x, w3_.y,  \
                         w3_.z, w3_.w, w4_.x, w4_.y, w4_.z, w4_.w, w5_.x,  \
                         w5_.y, w5_.z, w5_.w};                             \
  float t0_ = 0.f, t1_ = 0.f, t2_ = 0.f;                                   \
  _Pragma("unroll") for (int r_ = 0; r_ < 8; ++r_) {                       \
    t0_ = fmaf(efs[r_], wv_[r_ * 3 + 0], t0_);                             \
    t1_ = fmaf(efs[r_], wv_[r_ * 3 + 1], t1_);                             \
    t2_ = fmaf(efs[r_], wv_[r_ * 3 + 2], t2_);                             \
  }                                                                        \
  t0_ *= (XS); t1_ *= (XS); t2_ *= (XS);                                   \
  accR[0] = fmaf(t0_, ers[0], accR[0]);                                    \
  accI[0] = fmaf(t0_, eis[0], accI[0]);                                    \
  _Pragma("unroll") for (int m_ = 1; m_ < 4; ++m_) {                       \
    accR[m_] = fmaf(t1_, ers[m_], accR[m_]);                               \
    accI[m_] = fmaf(t1_, eis[m_], accI[m_]);                               \
  }                                                                        \
  _Pragma("unroll") for (int m_ = 4; m_ < 9; ++m_) {                       \
    accR[m_] = fmaf(t2_, ers[m_], accR[m_]);                               \
    accI[m_] = fmaf(t2_, eis[m_], accI[m_]);                               \
  }                                                                        \
} while (0)

// FUSED gather + per-l linear. One node per wave, 8 waves (512 thr)/block.
__global__ __launch_bounds__(512, 2) void fused_kernel(
    const float* __restrict__ h, const int* __restrict__ offs,
    const float* __restrict__ blkd, const int* __restrict__ elist,
    const float* __restrict__ W_tpw, const float* __restrict__ W_linT,
    float* __restrict__ out) {
  __shared__ float lds[17920];  // 71680 B
  // stage W_tpw -> [a][u][28] with group rotation gp=(g+(u>>3))%7.
  // Each lane writes ITS OWN row via b128 -> write bank pattern == read
  // pattern (conflict-free), unlike lane-varying stride-28 dword writes.
  for (int t = threadIdx.x; t < AA * 6 * 64; t += 512) {
    int a = t / 384, rem = t - a * 384;
    int g = rem >> 6, u = rem & 63;
    int gp = g + (u >> 3); if (gp >= 7) gp -= 7;
    const float* src = W_tpw + a * 1536 + g * 256 + u;
    float4 w;
    w.x = src[0]; w.y = src[64]; w.z = src[128]; w.w = src[192];
    *(float4*)&lds[a * 1792 + u * 28 + gp * 4] = w;
  }
  __syncthreads();
  int wid = __builtin_amdgcn_readfirstlane(threadIdx.x >> 6);
  int lane = threadIdx.x & 63;
  int n = blockIdx.x * 8 + wid;  // wave-uniform
  int gpi[6];
#pragma unroll
  for (int g = 0; g < 6; ++g) {
    int t = g + (lane >> 3); gpi[g] = (t >= 7) ? t - 7 : t;
  }
  float accR[9], accI[9];
#pragma unroll
  for (int m = 0; m < 9; ++m) { accR[m] = 0.f; accI[m] = 0.f; }
  int beg = __builtin_amdgcn_readfirstlane(offs[n]);
  int cnt = __builtin_amdgcn_readfirstlane(offs[n + 1]) - beg;
  if (cnt > 0) {
    const int* bi = (const int*)blkd;
    int pairs = (cnt + 1) >> 1;
    // per-lane gather role: lanes 0-27 edgeA dwords, 28-55 edgeB, 56-63 dup A
    int lm = lane, roleB = 0;
    if (lane >= 28) { lm = lane - 28; roleB = 1; }
    if (lane >= 56) { lm = 0; roleB = 0; }
    // pair 0
    int ea0 = elist[beg];
    int eb0 = (cnt > 1) ? elist[beg + 1] : ea0;
    int blkP = bi[(size_t)(roleB ? eb0 : ea0) * 28 + lm];
    // pair 1
    int blkN = blkP;
    if (pairs > 1) {
      int ea1 = elist[beg + 2];
      int eb1 = (cnt > 3) ? elist[beg + 3] : ea1;
      blkN = bi[(size_t)(roleB ? eb1 : ea1) * 28 + lm];
    }
    // ids for pair 2 (gathered inside loop)
    int ean = 0, ebn = 0;
    if (pairs > 2) {
      ean = elist[beg + 4];
      ebn = (cnt > 5) ? elist[beg + 5] : ean;
    }
    int sA = RL(blkP, 0) & 0xFFFFF;
    int sB = RL(blkP, 28) & 0xFFFFF;
    float xsA = h[(size_t)sA * 64 + lane];
    float xsB = h[(size_t)sB * 64 + lane];
    for (int p = 0; p < pairs; ++p) {
      int blkNN = blkN;
      if (p + 2 < pairs)  // gather pair p+2 with ids loaded >=1 iter ago
        blkNN = bi[(size_t)(roleB ? ebn : ean) * 28 + lm];
      if (p + 3 < pairs) {  // refill ids for pair p+3
        ean = elist[beg + 2 * (p + 3)];
        ebn = (2 * (p + 3) + 1 < cnt) ? elist[beg + 2 * (p + 3) + 1] : ean;
      }
      float xsA2 = 0.f, xsB2 = 0.f;
      if (p + 1 < pairs) {  // h prefetch for pair p+1
        int sA2 = RL(blkN, 0) & 0xFFFFF;
        int sB2 = RL(blkN, 28) & 0xFFFFF;
        xsA2 = h[(size_t)sA2 * 64 + lane];
        xsB2 = h[(size_t)sB2 * 64 + lane];
      }
      EDGE(blkP, 0, xsA);
      if (2 * p + 1 < cnt) EDGE(blkP, 28, xsB);
      blkP = blkN; blkN = blkNN; xsA = xsA2; xsB = xsB2;
    }
  }
  __builtin_amdgcn_sched_barrier(0);
  // ---- channel mix via readlane: out[v][m] = sum_u acc[u][m] W[u][v] ----
  float outR[9], outI[9];
#pragma unroll
  for (int m = 0; m < 9; ++m) { outR[m] = 0.f; outI[m] = 0.f; }
  {  // l = 0, m = 0
    const float4* wt = (const float4*)(W_linT + (size_t)lane * 64);
    float4 wr[16];
#pragma unroll
    for (int q = 0; q < 16; ++q) wr[q] = wt[q];
    const float* wf = (const float*)wr;
#pragma unroll
    for (int u = 0; u < 64; ++u) {
      outR[0] = fmaf(RLF(__float_as_int(accR[0]), u), wf[u], outR[0]);
      outI[0] = fmaf(RLF(__float_as_int(accI[0]), u), wf[u], outI[0]);
    }
  }
  __builtin_amdgcn_sched_barrier(0);
  {  // l = 1, m in [1,4)
    const float4* wt = (const float4*)(W_linT + 4096 + (size_t)lane * 64);
    float4 wr[16];
#pragma unroll
    for (int q = 0; q < 16; ++q) wr[q] = wt[q];
    const float* wf = (const float*)wr;
#pragma unroll
    for (int u = 0; u < 64; ++u) {
#pragma unroll
      for (int m = 1; m < 4; ++m) {
        outR[m] = fmaf(RLF(__float_as_int(accR[m]), u), wf[u], outR[m]);
        outI[m] = fmaf(RLF(__float_as_int(accI[m]), u), wf[u], outI[m]);
      }
    }
  }
  __builtin_amdgcn_sched_barrier(0);
  {  // l = 2, m in [4,9)
    const float4* wt = (const float4*)(W_linT + 8192 + (size_t)lane * 64);
    float4 wr[16];
#pragma unroll
    for (int q = 0; q < 16; ++q) wr[q] = wt[q];
    const float* wf = (const float*)wr;
#pragma unroll
    for (int u = 0; u < 64; ++u) {
#pragma unroll
      for (int m = 4; m < 9; ++m) {
        outR[m] = fmaf(RLF(__float_as_int(accR[m]), u), wf[u], outR[m]);
        outI[m] = fmaf(RLF(__float_as_int(accI[m]), u), wf[u], outI[m]);
      }
    }
  }
  __builtin_amdgcn_sched_barrier(0);
  // ---- staged coalesced output (reuse LDS after all waves leave edge) ----
  __syncthreads();
  const float SCL = 0.0078125f;  // (1/sqrt(64))/16
  float* stg = lds + wid * 1152;
#pragma unroll
  for (int m = 0; m < 9; ++m) {
    stg[lane * 9 + m] = outR[m] * SCL;
    stg[576 + lane * 9 + m] = outI[m] * SCL;
  }
  __builtin_amdgcn_s_waitcnt(0);
#pragma unroll
  for (int k = 0; k < 9; ++k) {
    out[(size_t)n * 576 + k * 64 + lane] = stg[k * 64 + lane];
    out[NC9 + (size_t)n * 576 + k * 64 + lane] = stg[576 + k * 64 + lane];
  }
}

extern "C" void kernel_launch(void* const* d_in, const int* in_sizes, int n_in,
                              void* d_out, int out_size, void* d_ws, size_t ws_size,
                              hipStream_t stream) {
  const float* node_attrs = (const float*)d_in[0];
  const float* node_feats = (const float*)d_in[1];
  const float* ear        = (const float*)d_in[2];
  const float* eai        = (const float*)d_in[3];
  const float* ef         = (const float*)d_in[4];
  const int*   senders    = (const int*)d_in[5];
  const int*   receivers  = (const int*)d_in[6];
  const float* W_up       = (const float*)d_in[7];
  const float* W_tpw      = (const float*)d_in[8];
  const float* W_lin      = (const float*)d_in[9];
  const float* W_skip     = (const float*)d_in[10];
  float* out = (float*)d_out;

  char* ws = (char*)d_ws;
  float* h        = (float*)(ws + WS_H);
  float* blk      = (float*)(ws + WS_BLK);
  float* wlt      = (float*)(ws + WS_WLT);
  int*   species  = (int*)(ws + WS_SPECIES);
  int*   counts   = (int*)(ws + WS_COUNTS);
  int*   cursor   = (int*)(ws + WS_CURSOR);
  int*   offsets  = (int*)(ws + WS_OFFSETS);
  int*   elist    = (int*)(ws + WS_ELIST);

  // zero counts + cursor (contiguous 128 KB)
  hipMemsetAsync(ws + WS_COUNTS, 0, 128000, stream);

  species_kernel<<<63, 256, 0, stream>>>(node_attrs, species);
  node_kernel<<<4000, 256, 0, stream>>>(node_feats, species, W_up, W_skip, h, out);
  wlint_kernel<<<48, 256, 0, stream>>>(W_lin, wlt);
  hist_kernel<<<1000, 256, 0, stream>>>(receivers, counts);
  scan_kernel<<<1, 1024, 0, stream>>>(counts, offsets);
  fill_slots_kernel<<<1000, 256, 0, stream>>>(receivers, offsets, cursor, elist);
  build_blk_kernel<<<1000, 256, 0, stream>>>(senders, species, ef, ear, eai, blk);
  fused_kernel<<<2000, 512, 0, stream>>>(h, offsets, blk, elist, W_tpw, wlt, out);
}

// Round 7
// 348.407 us; speedup vs baseline: 1.0610x; 1.0610x over previous
//
#include <hip/hip_runtime.h>
#include <hip/hip_bf16.h>

#define NN 16000
#define EE 256000
#define CC 64
#define AA 10
#define RR 8
#define NC9 9216000      // N*C*9
#define SC_OFF 18432000  // 2*N*C*9

// ---------------- workspace layout (bytes) ----------------
#define WS_H        0
#define WS_BLK      4096000
#define WS_WLT      32768000
#define WS_SPECIES  32817152
#define WS_COUNTS   32881152
#define WS_CURSOR   32945152
#define WS_OFFSETS  33009152
#define WS_ELIST    33073216
// end ~34.1 MB

__device__ __forceinline__ float comp4(float4 v, int j) {
  return j == 0 ? v.x : j == 1 ? v.y : j == 2 ? v.z : v.w;
}

// species + histogram + W_lin transpose, one pass (grid covers E)
__global__ __launch_bounds__(256) void prep_kernel(
    const float* __restrict__ attrs, const int* __restrict__ recv,
    const float* __restrict__ W_lin, int* __restrict__ species,
    int* __restrict__ counts, float* __restrict__ wlt) {
  int i = blockIdx.x * 256 + threadIdx.x;
  if (i < NN) {
    const float* p = attrs + (size_t)i * AA;
    int sp = 0;
#pragma unroll
    for (int a = 1; a < AA; ++a)
      if (p[a] > 0.5f) sp = a;
    species[i] = sp;
  }
  if (i < 3 * 64 * 64) {  // wlt[l][v][u] = W_lin[l][u][v]
    int l = i >> 12, rem = i & 4095, v = rem >> 6, u = rem & 63;
    wlt[i] = W_lin[l * 4096 + u * 64 + v];
  }
  if (i < EE) atomicAdd(&counts[recv[i]], 1);
}

// single-block exclusive scan of counts[N] -> offsets[N+1]
__global__ __launch_bounds__(1024) void scan_kernel(
    const int* __restrict__ counts, int* __restrict__ offsets) {
  __shared__ int part[1024];
  int tid = threadIdx.x;
  const int CH = 16;
  int base = tid * CH;
  int loc[CH];
  int s = 0;
#pragma unroll
  for (int i = 0; i < CH; ++i) {
    int idx = base + i;
    int c = (idx < NN) ? counts[idx] : 0;
    loc[i] = c;
    s += c;
  }
  part[tid] = s;
  __syncthreads();
  for (int off = 1; off < 1024; off <<= 1) {
    int t = part[tid];
    int add = (tid >= off) ? part[tid - off] : 0;
    __syncthreads();
    part[tid] = t + add;
    __syncthreads();
  }
  int pre = (tid > 0) ? part[tid - 1] : 0;
#pragma unroll
  for (int i = 0; i < CH; ++i) {
    int idx = base + i;
    if (idx <= NN) offsets[idx] = pre;
    pre += loc[i];
  }
}

// CSR slot fill + packed 112-B per-EDGE block (coalesced, edge order):
// dw0 = s|(a<<20); dw1-8 = ef; dw9-17 = er; dw18-26 = ei; dw27 pad
__global__ __launch_bounds__(256) void edge_kernel(
    const int* __restrict__ recv, const int* __restrict__ senders,
    const int* __restrict__ species, const int* __restrict__ offsets,
    int* __restrict__ cursor, int* __restrict__ elist,
    const float* __restrict__ ef, const float* __restrict__ ear,
    const float* __restrict__ eai, float* __restrict__ blk) {
  int e = blockIdx.x * 256 + threadIdx.x;
  if (e >= EE) return;
  int r = recv[e];
  int pos = atomicAdd(&cursor[r], 1);
  elist[offsets[r] + pos] = e;
  int s = senders[e];
  int a = species[s];
  const float* efp = ef + (size_t)e * 8;
  const float* erp = ear + (size_t)e * 9;
  const float* eip = eai + (size_t)e * 9;
  float4* dst = (float4*)(blk + (size_t)e * 28);
  float4 q;
  q.x = __int_as_float(s | (a << 20)); q.y = efp[0]; q.z = efp[1]; q.w = efp[2];
  dst[0] = q;
  q.x = efp[3]; q.y = efp[4]; q.z = efp[5]; q.w = efp[6];
  dst[1] = q;
  q.x = efp[7]; q.y = erp[0]; q.z = erp[1]; q.w = erp[2];
  dst[2] = q;
  q.x = erp[3]; q.y = erp[4]; q.z = erp[5]; q.w = erp[6];
  dst[3] = q;
  q.x = erp[7]; q.y = erp[8]; q.z = eip[0]; q.w = eip[1];
  dst[4] = q;
  q.x = eip[2]; q.y = eip[3]; q.z = eip[4]; q.w = eip[5];
  dst[5] = q;
  q.x = eip[6]; q.y = eip[7]; q.z = eip[8]; q.w = 0.f;
  dst[6] = q;
}

// h = (nf @ W_up)/8 ; sc = (nf . W_skip[:,a,:])/sqrt(640). W_up in LDS.
__global__ __launch_bounds__(256) void node_kernel(
    const float* __restrict__ nf, const float* __restrict__ attrs,
    const float* __restrict__ W_up, const float* __restrict__ W_skip,
    float* __restrict__ h, float* __restrict__ out) {
  __shared__ float sW[4096];
  for (int t = threadIdx.x; t < 4096; t += 256) sW[t] = W_up[t];
  __syncthreads();
  int wid = __builtin_amdgcn_readfirstlane(threadIdx.x >> 6);
  int lane = threadIdx.x & 63;
  for (int n = blockIdx.x * 4 + wid; n < NN; n += 4000) {
    const float* ap = attrs + (size_t)n * AA;  // uniform -> s_load
    int a = 0;
#pragma unroll
    for (int j = 1; j < AA; ++j)
      if (ap[j] > 0.5f) a = j;
    const float* nfp = nf + (size_t)n * 64;
    const float* wsk = W_skip + (size_t)a * 64;
    float hacc = 0.f, sacc = 0.f;
#pragma unroll
    for (int u = 0; u < 64; ++u) {
      float x = nfp[u];  // uniform -> s_load
      hacc = fmaf(x, sW[u * 64 + lane], hacc);
      sacc = fmaf(x, wsk[u * 640 + lane], sacc);
    }
    h[(size_t)n * 64 + lane] = hacc * 0.125f;
    out[SC_OFF + (size_t)n * 64 + lane] = sacc * 0.03952847075210474f;
  }
}

#define RLF(V, L) __int_as_float(__builtin_amdgcn_readlane((V), (L)))

// one edge: payload in SGPR arrays, weights per-lane LDS b128, acc in VGPRs
#define EDGE2(EFA, ERA, EIA, PKV, XS) do {                                 \
  int a_ = (PKV) >> 20;                                                    \
  const float4* wp_ = (const float4*)(lds + a_ * 1792 + lane * 28);        \
  float4 w_[6];                                                            \
  _Pragma("unroll") for (int g_ = 0; g_ < 6; ++g_) w_[g_] = wp_[gpi[g_]];  \
  float t0_ = 0.f, t1_ = 0.f, t2_ = 0.f;                                   \
  _Pragma("unroll") for (int r_ = 0; r_ < 8; ++r_) {                       \
    t0_ = fmaf((EFA)[r_], comp4(w_[(r_ * 3 + 0) >> 2], (r_ * 3 + 0) & 3), t0_); \
    t1_ = fmaf((EFA)[r_], comp4(w_[(r_ * 3 + 1) >> 2], (r_ * 3 + 1) & 3), t1_); \
    t2_ = fmaf((EFA)[r_], comp4(w_[(r_ * 3 + 2) >> 2], (r_ * 3 + 2) & 3), t2_); \
  }                                                                        \
  t0_ *= (XS); t1_ *= (XS); t2_ *= (XS);                                   \
  accR[0] = fmaf(t0_, (ERA)[0], accR[0]);                                  \
  accI[0] = fmaf(t0_, (EIA)[0], accI[0]);                                  \
  _Pragma("unroll") for (int m_ = 1; m_ < 4; ++m_) {                       \
    accR[m_] = fmaf(t1_, (ERA)[m_], accR[m_]);                             \
    accI[m_] = fmaf(t1_, (EIA)[m_], accI[m_]);                             \
  }                                                                        \
  _Pragma("unroll") for (int m_ = 4; m_ < 9; ++m_) {                       \
    accR[m_] = fmaf(t2_, (ERA)[m_], accR[m_]);                             \
    accI[m_] = fmaf(t2_, (EIA)[m_], accI[m_]);                             \
  }                                                                        \
} while (0)

// mix: out[v][m] = sum_u acc[u][m] * W[u][v]; W per-lane from swizzled LDS
#define MIXL(LV, M0, M1)                                                    \
  _Pragma("unroll") for (int q_ = 0; q_ < 16; ++q_) {                       \
    float4 w4_ = *(const float4*)&lds[(LV) * 4096 + lane * 64 +             \
                                      ((q_ + lane) & 15) * 4];              \
    _Pragma("unroll") for (int j_ = 0; j_ < 4; ++j_) {                      \
      float wu_ = comp4(w4_, j_);                                           \
      _Pragma("unroll") for (int m_ = (M0); m_ < (M1); ++m_) {              \
        outR[m_] = fmaf(RLF(__float_as_int(accR[m_]), q_ * 4 + j_), wu_, outR[m_]); \
        outI[m_] = fmaf(RLF(__float_as_int(accI[m_]), q_ * 4 + j_), wu_, outI[m_]); \
      }                                                                     \
    }                                                                       \
  }

// FUSED gather + per-l linear. One node per wave, 8 waves/block, 2 blk/CU.
__global__ __launch_bounds__(512, 4) void fused_kernel(
    const float* __restrict__ h, const int* __restrict__ offs,
    const float* __restrict__ blkd, const int* __restrict__ elist,
    const float* __restrict__ W_tpw, const float* __restrict__ wlt,
    float* __restrict__ out) {
  __shared__ float lds[17920];  // 71680 B
  // stage W_tpw -> [a][u][28], group g at slot gp=(g+5u)%7 (balanced ~8/slot)
  for (int t = threadIdx.x; t < AA * 6 * 64; t += 512) {
    int a = t / 384, rem = t - a * 384;
    int g = rem >> 6, u = rem & 63;
    int gp = (g + 5 * u) % 7;
    const float* src = W_tpw + a * 1536 + g * 256 + u;  // k-major, stride 64
    float4 w;
    w.x = src[0]; w.y = src[64]; w.z = src[128]; w.w = src[192];
    *(float4*)&lds[a * 1792 + u * 28 + gp * 4] = w;
  }
  __syncthreads();
  int wid = __builtin_amdgcn_readfirstlane(threadIdx.x >> 6);
  int lane = threadIdx.x & 63;
  int n = blockIdx.x * 8 + wid;  // wave-uniform
  int gpi[6];
#pragma unroll
  for (int g = 0; g < 6; ++g) gpi[g] = (g + 5 * lane) % 7;
  float accR[9], accI[9];
#pragma unroll
  for (int m = 0; m < 9; ++m) { accR[m] = 0.f; accI[m] = 0.f; }
  int beg = __builtin_amdgcn_readfirstlane(offs[n]);
  int end_ = __builtin_amdgcn_readfirstlane(offs[n + 1]);
  if (end_ > beg) {
    const int* bi = (const int*)blkd;
    int e0 = elist[beg];                      // uniform -> s_load
    int pk0 = bi[(size_t)e0 * 28];
    int e1 = (beg + 1 < end_) ? elist[beg + 1] : e0;
    int pk1 = bi[(size_t)e1 * 28];
    float xs0 = h[(size_t)(pk0 & 0xFFFFF) * 64 + lane];  // coalesced
    float xs1 = h[(size_t)(pk1 & 0xFFFFF) * 64 + lane];
    float efc[8], erc[9], eic[9];
    {
      const float* ep = blkd + (size_t)e0 * 28;  // uniform -> s_load
#pragma unroll
      for (int i = 0; i < 8; ++i) efc[i] = ep[1 + i];
#pragma unroll
      for (int i = 0; i < 9; ++i) erc[i] = ep[9 + i];
#pragma unroll
      for (int i = 0; i < 9; ++i) eic[i] = ep[18 + i];
    }
    for (int idx = beg; idx < end_; ++idx) {
      // prefetch idx+2 id/pk/h (2-deep: covers elist->blk->h chain)
      int e2 = e0, pk2 = pk0;
      float xs2 = 0.f;
      if (idx + 2 < end_) {
        e2 = elist[idx + 2];
        pk2 = bi[(size_t)e2 * 28];
        xs2 = h[(size_t)(pk2 & 0xFFFFF) * 64 + lane];
      }
      // prefetch idx+1 payload (1-deep, covers SMEM latency under compute)
      float efn[8], ern[9], ein[9];
      if (idx + 1 < end_) {
        const float* ep = blkd + (size_t)e1 * 28;
#pragma unroll
        for (int i = 0; i < 8; ++i) efn[i] = ep[1 + i];
#pragma unroll
        for (int i = 0; i < 9; ++i) ern[i] = ep[9 + i];
#pragma unroll
        for (int i = 0; i < 9; ++i) ein[i] = ep[18 + i];
      } else {
#pragma unroll
        for (int i = 0; i < 8; ++i) efn[i] = 0.f;
#pragma unroll
        for (int i = 0; i < 9; ++i) { ern[i] = 0.f; ein[i] = 0.f; }
      }
      EDGE2(efc, erc, eic, pk0, xs0);
      pk0 = pk1; xs0 = xs1;
      e1 = e2; pk1 = pk2; xs1 = xs2;
#pragma unroll
      for (int i = 0; i < 8; ++i) efc[i] = efn[i];
#pragma unroll
      for (int i = 0; i < 9; ++i) { erc[i] = ern[i]; eic[i] = ein[i]; }
    }
  }
  __builtin_amdgcn_sched_barrier(0);
  __syncthreads();  // all waves done with W_tpw region
  // stage wlt -> lds[l][v][64], group q at slot (q+v)&15 (balanced)
  for (int t = threadIdx.x; t < 3072; t += 512) {
    int l = t >> 10, rem = t & 1023, v = rem >> 4, q = rem & 15;
    int slot = (q + v) & 15;
    float4 w = *(const float4*)(wlt + l * 4096 + v * 64 + q * 4);
    *(float4*)&lds[l * 4096 + v * 64 + slot * 4] = w;
  }
  __syncthreads();
  float outR[9], outI[9];
#pragma unroll
  for (int m = 0; m < 9; ++m) { outR[m] = 0.f; outI[m] = 0.f; }
  MIXL(0, 0, 1)
  MIXL(1, 1, 4)
  MIXL(2, 4, 9)
  // staged coalesced output; stg region (12288..16896) disjoint from W_lin
  const float SCL = 0.0078125f;  // (1/sqrt(64))/16
  float* stg = lds + 12288 + wid * 576;
#pragma unroll
  for (int m = 0; m < 9; ++m) stg[lane * 9 + m] = outR[m] * SCL;
  __builtin_amdgcn_s_waitcnt(0);
#pragma unroll
  for (int k = 0; k < 9; ++k)
    out[(size_t)n * 576 + k * 64 + lane] = stg[k * 64 + lane];
#pragma unroll
  for (int m = 0; m < 9; ++m) stg[lane * 9 + m] = outI[m] * SCL;
  __builtin_amdgcn_s_waitcnt(0);
#pragma unroll
  for (int k = 0; k < 9; ++k)
    out[NC9 + (size_t)n * 576 + k * 64 + lane] = stg[k * 64 + lane];
}

extern "C" void kernel_launch(void* const* d_in, const int* in_sizes, int n_in,
                              void* d_out, int out_size, void* d_ws, size_t ws_size,
                              hipStream_t stream) {
  const float* node_attrs = (const float*)d_in[0];
  const float* node_feats = (const float*)d_in[1];
  const float* ear        = (const float*)d_in[2];
  const float* eai        = (const float*)d_in[3];
  const float* ef         = (const float*)d_in[4];
  const int*   senders    = (const int*)d_in[5];
  const int*   receivers  = (const int*)d_in[6];
  const float* W_up       = (const float*)d_in[7];
  const float* W_tpw      = (const float*)d_in[8];
  const float* W_lin      = (const float*)d_in[9];
  const float* W_skip     = (const float*)d_in[10];
  float* out = (float*)d_out;

  char* ws = (char*)d_ws;
  float* h        = (float*)(ws + WS_H);
  float* blk      = (float*)(ws + WS_BLK);
  float* wlt      = (float*)(ws + WS_WLT);
  int*   species  = (int*)(ws + WS_SPECIES);
  int*   counts   = (int*)(ws + WS_COUNTS);
  int*   cursor   = (int*)(ws + WS_CURSOR);
  int*   offsets  = (int*)(ws + WS_OFFSETS);
  int*   elist    = (int*)(ws + WS_ELIST);

  // zero counts + cursor (contiguous 128 KB)
  hipMemsetAsync(ws + WS_COUNTS, 0, 128000, stream);

  prep_kernel<<<1000, 256, 0, stream>>>(node_attrs, receivers, W_lin,
                                        species, counts, wlt);
  scan_kernel<<<1, 1024, 0, stream>>>(counts, offsets);
  edge_kernel<<<1000, 256, 0, stream>>>(receivers, senders, species, offsets,
                                        cursor, elist, ef, ear, eai, blk);
  node_kernel<<<1000, 256, 0, stream>>>(node_feats, node_attrs, W_up, W_skip,
                                        h, out);
  fused_kernel<<<2000, 512, 0, stream>>>(h, offsets, blk, elist, W_tpw, wlt,
                                         out);
}